// Round 2
// 318.333 us; speedup vs baseline: 1.0254x; 1.0254x over previous
//
#include <hip/hip_runtime.h>

// SelfAttention: x(8,2048,768) fp32, W_q/W_k/W_v (768,768) fp32 -> H fp32.
// Algebraic rewrite: S = x (Wq^T Wk / sqrt(D)) x^T:
//   cvt(x,Wv) ; transpose(Wq,Wk) ; G2 = NT(WkT,WqT)*scale ; T~ = NT(x,G2)
//   Vt = (x@Wv^T)^T ; P' = exp(NT(T~,x)) + rowsums ; H = NT(P',Vt)/rowsum
// GEMM core: 256x256 8-phase counted-vmcnt schedule (T2+T3+T4+T5):
//   8 waves (2Mx4N), BK=64, per-wave 128x64, acc[8][4].
//   LDS = exactly 128 KiB: 2 K-tile buffers x {A,B} x 2 k-half regions [256][32] halfs.
//   Per phase: {ds_read frags; 1 half-region global_load_lds prefetch; s_barrier;
//   lgkmcnt(0)+sched_barrier; setprio(1); 16 MFMA; setprio(0); [vmcnt(8)]; s_barrier}.
//   vmcnt counted (8 at phases 2,4 of each K-tile; never 0 in main loop).
//   Chunk swizzle c^=(row>>1)&3 applied on global source + ds_read addr (linear LDS dest).
//   MODE2's rowsum reciprocals computed in the epilogue (aliased LDS, vmcnt already 0).

typedef _Float16 f16;
typedef __attribute__((ext_vector_type(4))) _Float16 f16x4;
typedef __attribute__((ext_vector_type(8))) _Float16 f16x8;
typedef __attribute__((ext_vector_type(4))) float    f32x4;

#define SEQ   2048
#define DIM   768
#define NBAT  8
#define MTOT  (NBAT * SEQ)          // 16384
#define XN    ((long)MTOT * DIM)    // 12582912
#define WN    (DIM * DIM)           // 589824
#define SB    ((long)SEQ * SEQ)
#define QB    ((long)SEQ * DIM)
#define XN4   3145728               // XN/4
#define WN4   147456                // WN/4

__device__ __forceinline__ void async_cp16(const void* g, void* l) {
  __builtin_amdgcn_global_load_lds((__attribute__((address_space(1))) void*)g,
                                   (__attribute__((address_space(3))) void*)l,
                                   16, 0, 0);
}

// fp32 -> f16 for x and Wv.
__global__ void cvt_all(const float* __restrict__ x, const float* __restrict__ wv,
                        f16* __restrict__ x16, f16* __restrict__ wv16) {
  int i = blockIdx.x * 256 + threadIdx.x;      // float4 index
  const float* src; f16* dst; int idx;
  if (i < XN4) { src = x; dst = x16; idx = i; }
  else { src = wv; dst = wv16; idx = i - XN4; }
  float4 v = ((const float4*)src)[idx];
  f16x4 o = {(f16)v.x, (f16)v.y, (f16)v.z, (f16)v.w};
  ((f16x4*)dst)[idx] = o;
}

// Wq,Wk fp32 -> transposed f16 (WT[d][k] = W[k][d]).
__global__ void transpose_w(const float* __restrict__ wq, const float* __restrict__ wk,
                            f16* __restrict__ wqt, f16* __restrict__ wkt) {
  __shared__ float t[32][33];
  const float* src = blockIdx.z ? wk : wq;
  f16* dst = blockIdx.z ? wkt : wqt;
  const int bx = blockIdx.x * 32, by = blockIdx.y * 32;
  const int tx = threadIdx.x & 31, ty = threadIdx.x >> 5;   // 32 x 8
#pragma unroll
  for (int r = 0; r < 4; ++r)
    t[ty + 8 * r][tx] = src[(long)(by + ty + 8 * r) * DIM + bx + tx];
  __syncthreads();
#pragma unroll
  for (int r = 0; r < 4; ++r)
    dst[(long)(bx + ty + 8 * r) * DIM + by + tx] = (f16)t[tx][ty + 8 * r];
}

// ---------------- 256x256 8-phase NT GEMM ----------------
// MODE 0: f16 row-major out, scaled by `scale`.
// MODE 1: f16 out = exp(acc); rowsum partials -> Rsum[z][32][2048].
// MODE 2: fp32 out = acc * (1/rowsum) from Rsum partials.
// MODE 3: f16 transposed out Vt[b][n][m-local]. SWAP=false.
// SWAP=true: mfma(bf,af): m = lane&15 side, regs = 4 consecutive n.

#define STG_A(B_, S_, KK_) do { \
    f16* d_ = smA + ((B_) * 2 + (S_)) * 8192 + (tid << 3); \
    const f16* s_ = gA + (KK_) + (S_) * 32; \
    async_cp16(s_, d_); async_cp16(s_ + rK, d_ + 4096); } while (0)
#define STG_B(B_, S_, KK_) do { \
    f16* d_ = smB + ((B_) * 2 + (S_)) * 8192 + (tid << 3); \
    const f16* s_ = gB + (KK_) + (S_) * 32; \
    async_cp16(s_, d_); async_cp16(s_ + rK, d_ + 4096); } while (0)
#define VMW(n_) asm volatile("s_waitcnt vmcnt(" #n_ ")" ::: "memory")
#define NOW ((void)0)

#define MFMA4(MH_, I_, AF_) do { \
    _Pragma("unroll") \
    for (int j = 0; j < 4; ++j) \
      acc[(MH_) * 4 + (I_)][j] = SWAP \
        ? __builtin_amdgcn_mfma_f32_16x16x32_f16(bf[j], AF_, acc[(MH_) * 4 + (I_)][j], 0, 0, 0) \
        : __builtin_amdgcn_mfma_f32_16x16x32_f16(AF_, bf[j], acc[(MH_) * 4 + (I_)][j], 0, 0, 0); \
  } while (0)

#define PHASE(MH_, S_, STG_, W_) do { \
    const f16* Ar_ = smA + (buf * 2 + (S_)) * 8192 + aoff + (MH_) * 2048; \
    f16x8 a0_ = *(const f16x8*)(Ar_); \
    f16x8 a1_ = *(const f16x8*)(Ar_ + 512); \
    f16x8 a2_ = *(const f16x8*)(Ar_ + 1024); \
    f16x8 a3_ = *(const f16x8*)(Ar_ + 1536); \
    if ((MH_) == 0) { \
      const f16* Br_ = smB + (buf * 2 + (S_)) * 8192 + boff; \
      bf[0] = *(const f16x8*)(Br_); \
      bf[1] = *(const f16x8*)(Br_ + 512); \
      bf[2] = *(const f16x8*)(Br_ + 1024); \
      bf[3] = *(const f16x8*)(Br_ + 1536); \
    } \
    STG_; \
    __builtin_amdgcn_s_barrier(); \
    asm volatile("s_waitcnt lgkmcnt(0)" ::: "memory"); \
    __builtin_amdgcn_sched_barrier(0); \
    __builtin_amdgcn_s_setprio(1); \
    MFMA4(MH_, 0, a0_); MFMA4(MH_, 1, a1_); MFMA4(MH_, 2, a2_); MFMA4(MH_, 3, a3_); \
    __builtin_amdgcn_s_setprio(0); \
    W_; \
    __builtin_amdgcn_s_barrier(); \
    __builtin_amdgcn_sched_barrier(0); \
  } while (0)

template <int MODE, bool SWAP>
__global__ __launch_bounds__(512, 2)
void gemm_nt(const f16* __restrict__ Abase, long sAz,
             const f16* __restrict__ Bbase, long sBz,
             void* __restrict__ Cbase, long sCz,
             float* __restrict__ Rsum,
             int N, int K, float scale)
{
  __shared__ __align__(16) char smem[131072];   // exactly 128 KiB; epilogue aliases
  f16* smA = (f16*)smem;                        // 4 regions [256][32] halfs
  f16* smB = smA + 32768;

  const int tid  = threadIdx.x;
  const int z    = blockIdx.z;
  const int m0   = blockIdx.x * 256;
  const int n0   = blockIdx.y * 256;
  const int wave = tid >> 6;
  const int lane = tid & 63;
  const int wr   = wave >> 2;         // 0..1  (M half)
  const int wc   = wave & 3;          // 0..3  (N quarter)

  const f16* A = Abase + (long)z * sAz;
  const f16* B = Bbase + (long)z * sBz;

  // staging: thread t stages 2x16B per half-region; rows r0 and r0+128, chunk tid&3,
  // global chunk inverse-swizzled by (row>>1)&3 (same for r0 and r0+128).
  const int r0 = tid >> 2;
  const int gc = ((tid & 3) ^ ((tid >> 3) & 3)) * 8;
  const f16* gA = A + (long)(m0 + r0) * K + gc;
  const f16* gB = B + (long)(n0 + r0) * K + gc;
  const long rK = (long)128 * K;

  // fragment addressing: row = <base16k> + frow, chunk = q ^ ((frow>>1)&3)
  const int frow = lane & 15;
  const int q    = lane >> 4;
  const int cq   = (q ^ ((frow >> 1) & 3)) * 8;
  const int aoff = wr * 4096 + frow * 32 + cq;
  const int boff = wc * 2048 + frow * 32 + cq;

  f32x4 acc[8][4] = {};
  f16x8 bf[4];
  int buf = 0;
  const int NT = K >> 6;

  // prologue: tile0 {As0,Bs0,As1,Bs1} -> buf0, tile1 {As0,Bs0} -> buf1
  STG_A(0, 0, 0);  STG_B(0, 0, 0);
  STG_A(0, 1, 0);  STG_B(0, 1, 0);
  STG_A(1, 0, 64); STG_B(1, 0, 64);
  VMW(8);                       // s0(tile0) landed; 8 loads in flight
  __builtin_amdgcn_s_barrier();
  __builtin_amdgcn_sched_barrier(0);

  for (int t = 0; t + 2 < NT; ++t) {
    const int k1 = (t + 1) << 6, k2 = (t + 2) << 6;
    const int bn = buf ^ 1;
    PHASE(0, 0, STG_A(bn, 1, k1), NOW);      // stage As1(t+1)
    PHASE(1, 0, STG_B(bn, 1, k1), VMW(8));   // stage Bs1(t+1); s1(t) guaranteed landed
    PHASE(0, 1, STG_A(buf, 0, k2), NOW);     // stage As0(t+2) (s0(t) reads drained)
    PHASE(1, 1, STG_B(buf, 0, k2), VMW(8));  // stage Bs0(t+2); s0(t+1) guaranteed
    buf = bn;
  }
  { // tail: tiles NT-2 (buf) and NT-1 (buf^1)
    const int kl = (NT - 1) << 6;
    const int bn = buf ^ 1;
    STG_A(bn, 1, kl); STG_B(bn, 1, kl);      // last missing halves: s1(NT-1)
    VMW(4);                                  // everything except s1(NT-1) landed
    PHASE(0, 0, NOW, NOW);
    PHASE(1, 0, NOW, NOW);
    PHASE(0, 1, NOW, NOW);
    PHASE(1, 1, NOW, VMW(0));                // s1(NT-1) landed
    buf = bn;
    PHASE(0, 0, NOW, NOW);
    PHASE(1, 0, NOW, NOW);
    PHASE(0, 1, NOW, NOW);
    PHASE(1, 1, NOW, NOW);
  }

  // ---- epilogues (smem aliased; vmcnt drained to 0 by tail) ----
  const int TS = 272;   // f16 tile stride (halfs), 16B-aligned rows
  // output mapping (SWAP=true): m = wr*128 + ii*16 + frow ; n = wc*64 + j*16 + q*4 + r
  // (SWAP=false / MODE3):       n = wc*64 + j*16 + frow ; m = wr*128 + ii*16 + q*4 + r

  if constexpr (MODE == 0 || MODE == 1) {
    f16* T = (f16*)smem;   // [128][TS]
    f16* C = (f16*)Cbase + (long)z * sCz;
    const float sc = (MODE == 0) ? scale : 1.0f;
    float rs[8] = {};
#pragma unroll
    for (int p = 0; p < 2; ++p) {
      if (wr == p) {
#pragma unroll
        for (int ii = 0; ii < 8; ++ii)
#pragma unroll
          for (int j = 0; j < 4; ++j) {
            f16x4 v;
#pragma unroll
            for (int r = 0; r < 4; ++r) {
              float xv = acc[ii][j][r];
              if (MODE == 1) xv = __expf(xv); else xv *= sc;
              v[r] = (f16)xv;
              if (MODE == 1) rs[ii] += (float)v[r];   // sum of f16-rounded values
            }
            *(f16x4*)&T[(ii * 16 + frow) * TS + wc * 64 + j * 16 + q * 4] = v;
          }
      }
      __syncthreads();
      const int row = tid >> 2;
#pragma unroll
      for (int k = 0; k < 8; ++k) {
        const int ch = (tid & 3) + 4 * k;
        f16x8 v = *(const f16x8*)&T[row * TS + ch * 8];
        *(f16x8*)&C[(long)(m0 + p * 128 + row) * N + n0 + ch * 8] = v;
      }
      if (p == 0) __syncthreads();
    }
    if constexpr (MODE == 1) {
#pragma unroll
      for (int ii = 0; ii < 8; ++ii) {
        rs[ii] += __shfl_xor(rs[ii], 16);
        rs[ii] += __shfl_xor(rs[ii], 32);   // full 64-col segment sum
      }
      if (lane < 16) {   // q==0 lanes hold reduced sums; frow==lane
        float* rp = Rsum + ((long)z * 32 + blockIdx.y * 4 + wc) * SEQ + m0 + wr * 128;
#pragma unroll
        for (int ii = 0; ii < 8; ++ii) rp[ii * 16 + frow] = rs[ii];
      }
    }
  }

  if constexpr (MODE == 3) {   // Vt[b][d][s]; SWAP=false
    f16* T = (f16*)smem;       // [128 n-rows][TS] holding m(=s) contiguous
    f16* C = (f16*)Cbase;
    const int b = m0 >> 11, sl = m0 & 2047;
#pragma unroll
    for (int p = 0; p < 2; ++p) {
      if ((wc >> 1) == p) {
#pragma unroll
        for (int ii = 0; ii < 8; ++ii)
#pragma unroll
          for (int j = 0; j < 4; ++j) {
            f16x4 v = {(f16)acc[ii][j][0], (f16)acc[ii][j][1],
                       (f16)acc[ii][j][2], (f16)acc[ii][j][3]};
            *(f16x4*)&T[((wc & 1) * 64 + j * 16 + frow) * TS + wr * 128 + ii * 16 + q * 4] = v;
          }
      }
      __syncthreads();
      const int row = tid >> 2;
#pragma unroll
      for (int k = 0; k < 8; ++k) {
        const int ch = (tid & 3) + 4 * k;
        f16x8 v = *(const f16x8*)&T[row * TS + ch * 8];
        *(f16x8*)&C[(long)b * QB + (long)(n0 + p * 128 + row) * SEQ + sl + ch * 8] = v;
      }
      if (p == 0) __syncthreads();
    }
  }

  if constexpr (MODE == 2) {   // fp32 out, normalized; 4 passes of 64 rows
    // rowsum reciprocals: computed here (post-loop, vmcnt pure), aliased at 100 KiB
    float* sinv = (float*)(smem + 102400);   // 1 KiB, disjoint from Tf (66 KiB)
    if (tid < 256) {
      const float* rp = Rsum + (long)z * 32 * SEQ + m0 + tid;
      float s = 0.f;
#pragma unroll
      for (int k = 0; k < 32; ++k) s += rp[k * SEQ];
      sinv[tid] = 1.0f / s;
    }
    __syncthreads();
    float inv[8];
#pragma unroll
    for (int ii = 0; ii < 8; ++ii) inv[ii] = sinv[wr * 128 + ii * 16 + frow];
    float* Tf = (float*)smem;  // [64][FS] fp32
    const int FS = 264;
    float* C = (float*)Cbase + (long)z * sCz;
#pragma unroll
    for (int p = 0; p < 4; ++p) {
      if (wr == (p >> 1)) {
        const int ib = (p & 1) * 4;
#pragma unroll
        for (int i2 = 0; i2 < 4; ++i2)
#pragma unroll
          for (int j = 0; j < 4; ++j) {
            f32x4 v = acc[ib + i2][j] * inv[ib + i2];
            *(f32x4*)&Tf[(i2 * 16 + frow) * FS + wc * 64 + j * 16 + q * 4] = v;
          }
      }
      __syncthreads();
      const int row = tid >> 3;
#pragma unroll
      for (int k = 0; k < 8; ++k) {
        const int ch = (tid & 7) + 8 * k;
        f32x4 v = *(const f32x4*)&Tf[row * FS + ch * 4];
        *(f32x4*)&C[(long)(m0 + p * 64 + row) * N + n0 + ch * 4] = v;
      }
      if (p < 3) __syncthreads();
    }
  }
}

extern "C" void kernel_launch(void* const* d_in, const int* in_sizes, int n_in,
                              void* d_out, int out_size, void* d_ws, size_t ws_size,
                              hipStream_t stream) {
  const float* x  = (const float*)d_in[0];
  const float* Wq = (const float*)d_in[1];
  const float* Wk = (const float*)d_in[2];
  const float* Wv = (const float*)d_in[3];

  f16* ws    = (f16*)d_ws;
  f16* x16   = ws;                  // XN
  f16* Wv16  = x16 + XN;            // WN
  f16* WqT16 = Wv16 + WN;           // WN
  f16* WkT16 = WqT16 + WN;          // WN
  f16* G2    = WkT16 + WN;          // WN   G2[e][d] = sum_k Wk[k][e]Wq[k][d] * scale
  f16* T16   = G2 + WN;             // XN   T~ = x @ G2^T
  f16* Vt16  = T16 + XN;            // XN   [b][d][s]
  f16* S16   = Vt16 + XN;           // NBAT*SB (exp scores, unnormalized)
  float* rsumP = (float*)(S16 + (long)NBAT * SB);   // [8][32][2048] partials

  cvt_all<<<(XN4 + WN4) / 256, 256, 0, stream>>>(x, Wv, x16, Wv16);
  transpose_w<<<dim3(24, 24, 2), 256, 0, stream>>>(Wq, Wk, WqT16, WkT16);

  dim3 blk(512);
  // G2 = NT(WkT, WqT) * 1/sqrt(768)  (768x768x768)
  gemm_nt<0, true><<<dim3(3, 3, 1), blk, 0, stream>>>(
      WkT16, 0L, WqT16, 0L, (void*)G2, 0L, nullptr, DIM, DIM, 0.03608439182435161f);
  // T~ = NT(x16, G2)  (16384x768x768)
  gemm_nt<0, true><<<dim3(MTOT / 256, DIM / 256, 1), blk, 0, stream>>>(
      x16, 0L, G2, 0L, (void*)T16, 0L, nullptr, DIM, DIM, 1.0f);
  // Vt = (x @ Wv^T)^T per batch  (16384x768x768, transposed out)
  gemm_nt<3, false><<<dim3(MTOT / 256, DIM / 256, 1), blk, 0, stream>>>(
      x16, 0L, Wv16, 0L, (void*)Vt16, 0L, nullptr, DIM, DIM, 1.0f);
  // P' = exp(T~ x^T) per batch + rowsum partials  (2048x2048x768 x8)
  gemm_nt<1, true><<<dim3(SEQ / 256, SEQ / 256, NBAT), blk, 0, stream>>>(
      T16, QB, x16, QB, (void*)S16, SB, rsumP, SEQ, DIM, 1.0f);
  // H = (P' @ Vt^T) / rowsum, fp32  (2048x768x2048 x8)
  gemm_nt<2, true><<<dim3(SEQ / 256, DIM / 256, NBAT), blk, 0, stream>>>(
      S16, SB, Vt16, QB, d_out, QB, rsumP, DIM, SEQ, 1.0f);
}